// Round 10
// baseline (340.181 us; speedup 1.0000x reference)
//
#include <hip/hip_runtime.h>
#include <hip/hip_bf16.h>

#define NN    100000
#define NEDGE 1250000

typedef __attribute__((ext_vector_type(8))) short bf16x8;
typedef __attribute__((ext_vector_type(8))) unsigned short u16x8;
typedef __attribute__((ext_vector_type(4))) float f32x4;

__device__ __forceinline__ short f2bf(float f) {
    unsigned u = __float_as_uint(f);
    u += 0x7FFFu + ((u >> 16) & 1u);   // round-to-nearest-even
    return (short)(u >> 16);
}
__device__ __forceinline__ float bf2f(unsigned short u) {
    return __uint_as_float(((unsigned)u) << 16);
}

// ws layout (bytes)
constexpr size_t OFF_Q    = 0;                                   // f32 [NN*64]
constexpr size_t OFF_KB   = OFF_Q    + (size_t)NN * 64 * 4;      // bf16 [NN*64]
constexpr size_t OFF_VB   = OFF_KB   + (size_t)NN * 64 * 2;      // bf16 [NN*64]
constexpr size_t OFF_SRT  = OFF_VB   + (size_t)NN * 64 * 2;      // int2 [NEDGE] {src, eid} sorted by dst
constexpr size_t OFF_HIST = OFF_SRT  + (size_t)NEDGE * 8;
constexpr size_t OFF_EX   = OFF_HIST + (size_t)NN * 4;
constexpr size_t OFF_BSUM = OFF_EX   + (size_t)NN * 4;
constexpr size_t OFF_BOFF = OFF_BSUM + 512 * 4;
constexpr size_t OFF_START= OFF_BOFF + 512 * 4;
constexpr size_t OFF_CUR  = OFF_START+ (size_t)(NN + 1) * 4;
constexpr size_t WS_NEED  = OFF_CUR  + (size_t)NN * 4;           // ~63 MB
constexpr int NB_SCAN = (NN + 255) / 256;                         // 391

// ---------------- Q,K,V = x @ {WQ,WK,WV}; Q f32, K/V bf16 -----------------
__global__ __launch_bounds__(256) void qkv_kernel(
    const float* __restrict__ x,
    const float* __restrict__ WQ, const float* __restrict__ WK,
    const float* __restrict__ WV,
    float* __restrict__ Qf, unsigned short* __restrict__ Kb,
    unsigned short* __restrict__ Vb)
{
    const int lane = threadIdx.x & 63;
    const int wid  = threadIdx.x >> 6;
    const int gw   = blockIdx.x * 4 + wid;
    const int nw   = gridDim.x * 4;
    const int colb = lane & 15;
    const int krow = (lane >> 4) * 8;

    bf16x8 Bf[3][4][2];
    const float* Ws[3] = {WQ, WK, WV};
    #pragma unroll
    for (int m = 0; m < 3; ++m)
        #pragma unroll
        for (int n = 0; n < 4; ++n)
            #pragma unroll
            for (int kh = 0; kh < 2; ++kh) {
                bf16x8 b;
                #pragma unroll
                for (int j = 0; j < 8; ++j)
                    b[j] = f2bf(Ws[m][(size_t)(kh * 32 + krow + j) * 64 + n * 16 + colb]);
                Bf[m][n][kh] = b;
            }

    for (int tile = gw; tile < NN / 16; tile += nw) {
        const int r0 = tile * 16;
        const float* xr = x + (size_t)(r0 + colb) * 64 + krow;
        f32x4 a0 = *(const f32x4*)(xr);
        f32x4 a1 = *(const f32x4*)(xr + 4);
        f32x4 a2 = *(const f32x4*)(xr + 32);
        f32x4 a3 = *(const f32x4*)(xr + 36);
        bf16x8 Alo, Ahi;
        #pragma unroll
        for (int j = 0; j < 4; ++j) {
            Alo[j]     = f2bf(a0[j]);
            Alo[4 + j] = f2bf(a1[j]);
            Ahi[j]     = f2bf(a2[j]);
            Ahi[4 + j] = f2bf(a3[j]);
        }
        #pragma unroll
        for (int m = 0; m < 3; ++m) {
            #pragma unroll
            for (int n = 0; n < 4; ++n) {
                f32x4 acc = {0.f, 0.f, 0.f, 0.f};
                acc = __builtin_amdgcn_mfma_f32_16x16x32_bf16(Alo, Bf[m][n][0], acc, 0, 0, 0);
                acc = __builtin_amdgcn_mfma_f32_16x16x32_bf16(Ahi, Bf[m][n][1], acc, 0, 0, 0);
                #pragma unroll
                for (int q = 0; q < 4; ++q) {
                    const size_t idx = (size_t)(r0 + (lane >> 4) * 4 + q) * 64 + n * 16 + colb;
                    if (m == 0)      Qf[idx] = acc[q];
                    else if (m == 1) Kb[idx] = (unsigned short)f2bf(acc[q]);
                    else             Vb[idx] = (unsigned short)f2bf(acc[q]);
                }
            }
        }
    }
}

// ---------------- counting sort by dst -----------------------------------
__global__ void zero_hist_kernel(int* __restrict__ hist) {
    const int i = blockIdx.x * blockDim.x + threadIdx.x;
    if (i < NN) hist[i] = 0;
}

__global__ void hist_kernel(const int* __restrict__ ei, int* __restrict__ hist) {
    const int e = blockIdx.x * blockDim.x + threadIdx.x;
    if (e < NEDGE) atomicAdd(&hist[ei[NEDGE + e]], 1);
}

__global__ __launch_bounds__(256) void scanA_kernel(
    const int* __restrict__ hist, int* __restrict__ ex, int* __restrict__ bsum)
{
    __shared__ int wsum[4];
    const int i = blockIdx.x * 256 + threadIdx.x;
    const int lane = threadIdx.x & 63, wid = threadIdx.x >> 6;
    const int v = (i < NN) ? hist[i] : 0;
    int incl = v;
    #pragma unroll
    for (int off = 1; off < 64; off <<= 1) {
        int t = __shfl_up(incl, off);
        if (lane >= off) incl += t;
    }
    if (lane == 63) wsum[wid] = incl;
    __syncthreads();
    int pre = 0, bt = 0;
    #pragma unroll
    for (int w = 0; w < 4; ++w) { int s = wsum[w]; bt += s; if (w < wid) pre += s; }
    if (i < NN) ex[i] = incl - v + pre;
    if (threadIdx.x == 0) bsum[blockIdx.x] = bt;
}

__global__ __launch_bounds__(512) void scanB_kernel(
    const int* __restrict__ bsum, int* __restrict__ boff)
{
    __shared__ int wsum[8];
    const int i = threadIdx.x;
    const int lane = i & 63, wid = i >> 6;
    const int v = (i < NB_SCAN) ? bsum[i] : 0;
    int incl = v;
    #pragma unroll
    for (int off = 1; off < 64; off <<= 1) {
        int t = __shfl_up(incl, off);
        if (lane >= off) incl += t;
    }
    if (lane == 63) wsum[wid] = incl;
    __syncthreads();
    int pre = 0;
    #pragma unroll
    for (int w = 0; w < 8; ++w) { if (w < wid) pre += wsum[w]; }
    if (i < NB_SCAN) boff[i] = incl - v + pre;
}

__global__ void scanC_kernel(const int* __restrict__ ex, const int* __restrict__ boff,
                             int* __restrict__ start, int* __restrict__ cursor)
{
    const int i = blockIdx.x * blockDim.x + threadIdx.x;
    if (i < NN) {
        const int s = ex[i] + boff[i >> 8];
        start[i] = s;
        cursor[i] = s;
    } else if (i == NN) {
        start[NN] = NEDGE;
    }
}

__global__ void scatter_kernel(const int* __restrict__ ei, int* __restrict__ cursor,
                               int2* __restrict__ sorted)
{
    const int e = blockIdx.x * blockDim.x + threadIdx.x;
    if (e < NEDGE) {
        const int dst = ei[NEDGE + e];
        const int pos = atomicAdd(&cursor[dst], 1);
        sorted[pos] = make_int2(ei[e], e);
    }
}

// ---------------- fused aggregation, depth-3 staggered pipeline -----------
// One wave per dst. Iteration for d0 issues EXACTLY three load groups, each
// depending only on data that arrived >=1 iteration ago:
//   start[d0+3nw] (independent), sorted[d0+2nw] (uses beg2 from last iter),
//   edge_attr[d0+nw] (uses se1 from last iter).
// -> no intra-iteration dependent s_waitcnt chains; every load has a full
// iteration to land. K/V/Q for d0 issue at top, covered by phase A.
__global__ __launch_bounds__(256) void agg_kernel(
    const float* __restrict__ Qn, const unsigned short* __restrict__ Kb,
    const unsigned short* __restrict__ Vb,
    const float* __restrict__ edge_attr, const float* __restrict__ WE,
    const int* __restrict__ start, const int2* __restrict__ sorted,
    float* __restrict__ out)
{
    const int lane = threadIdx.x & 63;
    const int wid  = threadIdx.x >> 6;
    const int gw   = (blockIdx.x * blockDim.x + threadIdx.x) >> 6;
    const int nw   = (gridDim.x * blockDim.x) >> 6;
    const int colb = lane & 15;
    const int krow = (lane >> 4) * 8;
    const int el   = lane >> 3;     // edge slot 0..7
    const int h    = lane & 7;      // head 0..7
    const float c  = 0.35355339059327373f;   // 1/sqrt(8)

    __shared__ float efs_all[4][16][68];
    float (*efs)[68] = efs_all[wid];

    // WE fragments: 4 col-tiles x 2 k-halves (32 VGPRs)
    bf16x8 Bf[4][2];
    #pragma unroll
    for (int n = 0; n < 4; ++n)
        #pragma unroll
        for (int kh = 0; kh < 2; ++kh) {
            bf16x8 b;
            #pragma unroll
            for (int j = 0; j < 8; ++j)
                b[j] = f2bf(WE[(size_t)(kh * 32 + krow + j) * 64 + n * 16 + colb]);
            Bf[n][kh] = b;
        }

    int dst = gw;                       // gw < 16384 < NN always
    const int d1p = dst + nw, d2p = d1p + nw;

    // ---- prologue: fill 3 pipeline stages ----
    int beg0 = start[dst], end0 = start[dst + 1];
    int beg1 = 0, end1 = 0, beg2 = 0, end2 = 0;
    if (d1p < NN) { beg1 = start[d1p]; end1 = start[d1p + 1]; }
    if (d2p < NN) { beg2 = start[d2p]; end2 = start[d2p + 1]; }
    int2 se0, se1;
    { int r = beg0 + colb; if (r >= end0) r = beg0; se0 = sorted[r]; }
    { int r = beg1 + colb; if (r >= end1) r = beg1; se1 = sorted[r]; }
    f32x4 a0, a1, a2, a3;
    {
        const float* ear = edge_attr + (size_t)se0.y * 64 + krow;
        a0 = *(const f32x4*)(ear);
        a1 = *(const f32x4*)(ear + 4);
        a2 = *(const f32x4*)(ear + 32);
        a3 = *(const f32x4*)(ear + 36);
    }

    for (; dst < NN; dst += nw) {
        // ---- issue stage-3 loads (all address-independent this iteration) --
        const int d3 = dst + 3 * nw;
        int beg3 = 0, end3 = 0;
        if (d3 < NN) { beg3 = start[d3]; end3 = start[d3 + 1]; }

        int2 se2;
        { int r = beg2 + colb; if (r >= end2) r = beg2; se2 = sorted[r]; }

        f32x4 b0, b1, b2, b3;
        {
            const float* earn = edge_attr + (size_t)se1.y * 64 + krow;
            b0 = *(const f32x4*)(earn);
            b1 = *(const f32x4*)(earn + 4);
            b2 = *(const f32x4*)(earn + 32);
            b3 = *(const f32x4*)(earn + 36);
        }

        // ---- current-dst K/V/Q gathers (covered by phase A below) ---------
        const int s0 = __shfl(se0.x, el);
        const int s1 = __shfl(se0.x, el + 8);
        const u16x8 k0v = *(const u16x8*)(Kb + (size_t)s0 * 64 + h * 8);
        const u16x8 v0v = *(const u16x8*)(Vb + (size_t)s0 * 64 + h * 8);
        const u16x8 k1v = *(const u16x8*)(Kb + (size_t)s1 * 64 + h * 8);
        const u16x8 v1v = *(const u16x8*)(Vb + (size_t)s1 * 64 + h * 8);
        const float* qp = Qn + (size_t)dst * 64 + h * 8;
        const f32x4 q0 = *(const f32x4*)(qp);
        const f32x4 q1 = *(const f32x4*)(qp + 4);

        // ---- phase A: pack + MFMA -> efs (first 16-edge batch) -----------
        bf16x8 Alo, Ahi;
        #pragma unroll
        for (int jj = 0; jj < 4; ++jj) {
            Alo[jj]     = f2bf(a0[jj]);
            Alo[4 + jj] = f2bf(a1[jj]);
            Ahi[jj]     = f2bf(a2[jj]);
            Ahi[4 + jj] = f2bf(a3[jj]);
        }
        const int rbase = (lane >> 4) * 4;
        #pragma unroll
        for (int n = 0; n < 4; ++n) {
            f32x4 z = {0.f, 0.f, 0.f, 0.f};
            z = __builtin_amdgcn_mfma_f32_16x16x32_bf16(Alo, Bf[n][0], z, 0, 0, 0);
            z = __builtin_amdgcn_mfma_f32_16x16x32_bf16(Ahi, Bf[n][1], z, 0, 0, 0);
            #pragma unroll
            for (int q = 0; q < 4; ++q)
                efs[rbase + q][n * 16 + colb] = z[q];
        }

        // wave-private LDS; DS pipe in-order per wave
        asm volatile("s_waitcnt lgkmcnt(0)" ::: "memory");
        __builtin_amdgcn_sched_barrier(0);

        // ---- phase B: first batch scores + accumulate --------------------
        f32x4 av0 = {0,0,0,0}, av1 = {0,0,0,0};
        float az = 0.f;
        {
            const f32x4 e00 = *(const f32x4*)(&efs[el][h * 8]);
            const f32x4 e01 = *(const f32x4*)(&efs[el][h * 8 + 4]);
            const f32x4 e10 = *(const f32x4*)(&efs[el + 8][h * 8]);
            const f32x4 e11 = *(const f32x4*)(&efs[el + 8][h * 8 + 4]);
            float t0 = 0.f, t1 = 0.f;
            #pragma unroll
            for (int d = 0; d < 4; ++d) {
                t0 += bf2f(k0v[d])     * q0[d] * e00[d];
                t0 += bf2f(k0v[4 + d]) * q1[d] * e01[d];
                t1 += bf2f(k1v[d])     * q0[d] * e10[d];
                t1 += bf2f(k1v[4 + d]) * q1[d] * e11[d];
            }
            const bool act0 = (beg0 + el)     < end0;
            const bool act1 = (beg0 + el + 8) < end0;
            const float sc0 = act0 ? __expf(fminf(fmaxf(t0 * c, -5.f), 5.f)) : 0.f;
            const float sc1 = act1 ? __expf(fminf(fmaxf(t1 * c, -5.f), 5.f)) : 0.f;
            az += sc0 + sc1;
            #pragma unroll
            for (int d = 0; d < 4; ++d) {
                av0[d] += bf2f(v0v[d])     * sc0 + bf2f(v1v[d])     * sc1;
                av1[d] += bf2f(v0v[4 + d]) * sc0 + bf2f(v1v[4 + d]) * sc1;
            }
        }

        // ---- extra batches (deg > 16, ~13% of dsts): serial path ----------
        for (int j = beg0 + 16; j < end0; j += 16) {
            int rpos = j + colb;
            if (rpos >= end0) rpos = beg0;
            const int2 seb = sorted[rpos];
            const int sb0 = __shfl(seb.x, el);
            const int sb1 = __shfl(seb.x, el + 8);
            const u16x8 kb0 = *(const u16x8*)(Kb + (size_t)sb0 * 64 + h * 8);
            const u16x8 vb0 = *(const u16x8*)(Vb + (size_t)sb0 * 64 + h * 8);
            const u16x8 kb1 = *(const u16x8*)(Kb + (size_t)sb1 * 64 + h * 8);
            const u16x8 vb1 = *(const u16x8*)(Vb + (size_t)sb1 * 64 + h * 8);
            const float* earb = edge_attr + (size_t)seb.y * 64 + krow;
            const f32x4 c0 = *(const f32x4*)(earb);
            const f32x4 c1 = *(const f32x4*)(earb + 4);
            const f32x4 c2 = *(const f32x4*)(earb + 32);
            const f32x4 c3 = *(const f32x4*)(earb + 36);
            bf16x8 Blo, Bhi;
            #pragma unroll
            for (int jj = 0; jj < 4; ++jj) {
                Blo[jj]     = f2bf(c0[jj]);
                Blo[4 + jj] = f2bf(c1[jj]);
                Bhi[jj]     = f2bf(c2[jj]);
                Bhi[4 + jj] = f2bf(c3[jj]);
            }
            #pragma unroll
            for (int n = 0; n < 4; ++n) {
                f32x4 z = {0.f, 0.f, 0.f, 0.f};
                z = __builtin_amdgcn_mfma_f32_16x16x32_bf16(Blo, Bf[n][0], z, 0, 0, 0);
                z = __builtin_amdgcn_mfma_f32_16x16x32_bf16(Bhi, Bf[n][1], z, 0, 0, 0);
                #pragma unroll
                for (int q = 0; q < 4; ++q)
                    efs[rbase + q][n * 16 + colb] = z[q];
            }
            asm volatile("s_waitcnt lgkmcnt(0)" ::: "memory");
            __builtin_amdgcn_sched_barrier(0);
            const f32x4 e00 = *(const f32x4*)(&efs[el][h * 8]);
            const f32x4 e01 = *(const f32x4*)(&efs[el][h * 8 + 4]);
            const f32x4 e10 = *(const f32x4*)(&efs[el + 8][h * 8]);
            const f32x4 e11 = *(const f32x4*)(&efs[el + 8][h * 8 + 4]);
            float t0 = 0.f, t1 = 0.f;
            #pragma unroll
            for (int d = 0; d < 4; ++d) {
                t0 += bf2f(kb0[d])     * q0[d] * e00[d];
                t0 += bf2f(kb0[4 + d]) * q1[d] * e01[d];
                t1 += bf2f(kb1[d])     * q0[d] * e10[d];
                t1 += bf2f(kb1[4 + d]) * q1[d] * e11[d];
            }
            const bool act0 = (j + el)     < end0;
            const bool act1 = (j + el + 8) < end0;
            const float sc0 = act0 ? __expf(fminf(fmaxf(t0 * c, -5.f), 5.f)) : 0.f;
            const float sc1 = act1 ? __expf(fminf(fmaxf(t1 * c, -5.f), 5.f)) : 0.f;
            az += sc0 + sc1;
            #pragma unroll
            for (int d = 0; d < 4; ++d) {
                av0[d] += bf2f(vb0[d])     * sc0 + bf2f(vb1[d])     * sc1;
                av1[d] += bf2f(vb0[4 + d]) * sc0 + bf2f(vb1[4 + d]) * sc1;
            }
        }

        // ---- reduce across the 8 edge slots for each head -----------------
        #pragma unroll
        for (int off = 8; off < 64; off <<= 1) {
            az += __shfl_xor(az, off);
            #pragma unroll
            for (int d = 0; d < 4; ++d) {
                av0[d] += __shfl_xor(av0[d], off);
                av1[d] += __shfl_xor(av1[d], off);
            }
        }

        if (el == 0) {
            const float inv = 1.f / (az + 1e-6f);
            f32x4 o0, o1;
            #pragma unroll
            for (int d = 0; d < 4; ++d) { o0[d] = av0[d] * inv; o1[d] = av1[d] * inv; }
            float* op = out + (size_t)dst * 64 + h * 8;
            *(f32x4*)(op)     = o0;
            *(f32x4*)(op + 4) = o1;
        }

        // ---- rotate the pipeline -----------------------------------------
        beg0 = beg1; end0 = end1;
        beg1 = beg2; end1 = end2;
        beg2 = beg3; end2 = end3;
        se0 = se1; se1 = se2;
        a0 = b0; a1 = b1; a2 = b2; a3 = b3;
    }
}

// ---------------- fallback path (atomic, small ws) ------------------------
__global__ __launch_bounds__(256) void edge_kernel_fb(
    const float* __restrict__ edge_attr, const float* __restrict__ WE,
    const float* __restrict__ Qn, const unsigned short* __restrict__ Kb,
    const unsigned short* __restrict__ Vb, const int* __restrict__ ei,
    float* __restrict__ outAcc, float* __restrict__ Z)
{
    const int lane = threadIdx.x & 63;
    const int wid  = threadIdx.x >> 6;
    const int gw   = blockIdx.x * 4 + wid;
    const int nw   = gridDim.x * 4;
    const int colb = lane & 15;
    const int krow = (lane >> 4) * 8;
    const int b8   = (lane >> 3) & 1;

    bf16x8 Bf[4][2];
    #pragma unroll
    for (int n = 0; n < 4; ++n)
        #pragma unroll
        for (int kh = 0; kh < 2; ++kh) {
            bf16x8 b;
            #pragma unroll
            for (int j = 0; j < 8; ++j)
                b[j] = f2bf(WE[(size_t)(kh * 32 + krow + j) * 64 + n * 16 + colb]);
            Bf[n][kh] = b;
        }

    const float inv_sqrt_dh = 0.35355339059327373f;

    for (int tile = gw; tile < NEDGE / 16; tile += nw) {
        const int e0 = tile * 16;
        const float* ear = edge_attr + (size_t)(e0 + colb) * 64 + krow;
        f32x4 a0 = *(const f32x4*)(ear);
        f32x4 a1 = *(const f32x4*)(ear + 4);
        f32x4 a2 = *(const f32x4*)(ear + 32);
        f32x4 a3 = *(const f32x4*)(ear + 36);
        bf16x8 Alo, Ahi;
        #pragma unroll
        for (int j = 0; j < 4; ++j) {
            Alo[j]     = f2bf(a0[j]);
            Alo[4 + j] = f2bf(a1[j]);
            Ahi[j]     = f2bf(a2[j]);
            Ahi[4 + j] = f2bf(a3[j]);
        }
        f32x4 acc[4];
        #pragma unroll
        for (int n = 0; n < 4; ++n) {
            f32x4 z = {0.f, 0.f, 0.f, 0.f};
            z = __builtin_amdgcn_mfma_f32_16x16x32_bf16(Alo, Bf[n][0], z, 0, 0, 0);
            z = __builtin_amdgcn_mfma_f32_16x16x32_bf16(Ahi, Bf[n][1], z, 0, 0, 0);
            acc[n] = z;
        }
        int srcq[4], dstq[4];
        #pragma unroll
        for (int q = 0; q < 4; ++q) {
            const int erl = (lane >> 4) * 4 + q;
            srcq[q] = ei[e0 + erl];
            dstq[q] = ei[NEDGE + e0 + erl];
        }
        float sc[4][4];
        #pragma unroll
        for (int q = 0; q < 4; ++q) {
            #pragma unroll
            for (int n = 0; n < 4; ++n) {
                const int cidx = n * 16 + colb;
                const float kv = bf2f(Kb[(size_t)srcq[q] * 64 + cidx]);
                const float qv = Qn[(size_t)dstq[q] * 64 + cidx];
                float t = kv * qv * acc[n][q];
                t += __shfl_xor(t, 1);
                t += __shfl_xor(t, 2);
                t += __shfl_xor(t, 4);
                const float s = fminf(fmaxf(t * inv_sqrt_dh, -5.0f), 5.0f);
                sc[q][n] = __expf(s);
            }
        }
        #pragma unroll
        for (int q = 0; q < 4; ++q) {
            #pragma unroll
            for (int n = 0; n < 4; ++n) {
                const int cidx = n * 16 + colb;
                const float vv = bf2f(Vb[(size_t)srcq[q] * 64 + cidx]);
                unsafeAtomicAdd(&outAcc[(size_t)dstq[q] * 64 + cidx], vv * sc[q][n]);
                if ((lane & 7) == 0) {
                    const int hh = 2 * n + b8;
                    unsafeAtomicAdd(&Z[(size_t)dstq[q] * 8 + hh], sc[q][n]);
                }
            }
        }
    }
}

__global__ void finalize_fb(float* __restrict__ out, const float* __restrict__ Z) {
    const int i = blockIdx.x * blockDim.x + threadIdx.x;
    if (i < NN * 64) {
        const int node = i >> 6;
        const int h    = (i >> 3) & 7;
        out[i] = out[i] / (Z[node * 8 + h] + 1e-6f);
    }
}

extern "C" void kernel_launch(void* const* d_in, const int* in_sizes, int n_in,
                              void* d_out, int out_size, void* d_ws, size_t ws_size,
                              hipStream_t stream) {
    const float* x         = (const float*)d_in[0];
    const float* edge_attr = (const float*)d_in[1];
    const float* WQ        = (const float*)d_in[2];
    const float* WK        = (const float*)d_in[3];
    const float* WV        = (const float*)d_in[4];
    const float* WE        = (const float*)d_in[5];
    const int*   ei        = (const int*)d_in[6];
    float* out = (float*)d_out;

    char* base = (char*)d_ws;
    float*          Qf = (float*)(base + OFF_Q);
    unsigned short* Kb = (unsigned short*)(base + OFF_KB);
    unsigned short* Vb = (unsigned short*)(base + OFF_VB);

    qkv_kernel<<<1563, 256, 0, stream>>>(x, WQ, WK, WV, Qf, Kb, Vb);

    if (ws_size >= WS_NEED) {
        int2* sorted = (int2*)(base + OFF_SRT);
        int* hist    = (int*)(base + OFF_HIST);
        int* ex      = (int*)(base + OFF_EX);
        int* bsum    = (int*)(base + OFF_BSUM);
        int* boff    = (int*)(base + OFF_BOFF);
        int* start   = (int*)(base + OFF_START);
        int* cursor  = (int*)(base + OFF_CUR);

        zero_hist_kernel<<<NB_SCAN, 256, 0, stream>>>(hist);
        hist_kernel<<<(NEDGE + 255) / 256, 256, 0, stream>>>(ei, hist);
        scanA_kernel<<<NB_SCAN, 256, 0, stream>>>(hist, ex, bsum);
        scanB_kernel<<<1, 512, 0, stream>>>(bsum, boff);
        scanC_kernel<<<(NN + 256) / 256 + 1, 256, 0, stream>>>(ex, boff, start, cursor);
        scatter_kernel<<<(NEDGE + 255) / 256, 256, 0, stream>>>(ei, cursor, sorted);
        agg_kernel<<<4096, 256, 0, stream>>>(Qf, Kb, Vb, edge_attr, WE, start, sorted, out);
    } else {
        // fallback: atomic path
        float* Z = (float*)(base + OFF_SRT);
        hipMemsetAsync(d_out, 0, (size_t)NN * 64 * sizeof(float), stream);
        hipMemsetAsync(Z, 0, (size_t)NN * 8 * sizeof(float), stream);
        edge_kernel_fb<<<2048, 256, 0, stream>>>(edge_attr, WE, Qf, Kb, Vb, ei, out, Z);
        finalize_fb<<<(NN * 64 + 255) / 256, 256, 0, stream>>>(out, Z);
    }
}

// Round 11
// 315.456 us; speedup vs baseline: 1.0784x; 1.0784x over previous
//
#include <hip/hip_runtime.h>
#include <hip/hip_bf16.h>

#define NN    100000
#define NEDGE 1250000

typedef __attribute__((ext_vector_type(8))) short bf16x8;
typedef __attribute__((ext_vector_type(8))) unsigned short u16x8;
typedef __attribute__((ext_vector_type(4))) float f32x4;

__device__ __forceinline__ short f2bf(float f) {
    unsigned u = __float_as_uint(f);
    u += 0x7FFFu + ((u >> 16) & 1u);   // round-to-nearest-even
    return (short)(u >> 16);
}
__device__ __forceinline__ float bf2f(unsigned short u) {
    return __uint_as_float(((unsigned)u) << 16);
}

// ws layout (bytes)
constexpr size_t OFF_QB   = 0;                                   // bf16 [NN*64]
constexpr size_t OFF_KB   = OFF_QB   + (size_t)NN * 64 * 2;      // bf16 [NN*64]
constexpr size_t OFF_VB   = OFF_KB   + (size_t)NN * 64 * 2;      // bf16 [NN*64]
constexpr size_t OFF_SRT  = OFF_VB   + (size_t)NN * 64 * 2;      // int2 [NEDGE] {src, eid} sorted by dst
constexpr size_t OFF_HIST = OFF_SRT  + (size_t)NEDGE * 8;
constexpr size_t OFF_EX   = OFF_HIST + (size_t)NN * 4;
constexpr size_t OFF_BSUM = OFF_EX   + (size_t)NN * 4;
constexpr size_t OFF_START= OFF_BSUM + 512 * 4;
constexpr size_t OFF_CUR  = OFF_START+ (size_t)(NN + 1) * 4;
constexpr size_t WS_NEED  = OFF_CUR  + (size_t)NN * 4;           // ~50 MB
constexpr int NB_SCAN = (NN + 255) / 256;                         // 391

// ---------------- Q,K,V = x @ {WQ,WK,WV} -> bf16; also zeroes hist --------
__global__ __launch_bounds__(256) void qkv_kernel(
    const float* __restrict__ x,
    const float* __restrict__ WQ, const float* __restrict__ WK,
    const float* __restrict__ WV,
    unsigned short* __restrict__ Qb, unsigned short* __restrict__ Kb,
    unsigned short* __restrict__ Vb, int* __restrict__ hist)
{
    // fused zero_hist (qkv completes before hist_kernel launches)
    if (hist) {
        for (int i = blockIdx.x * blockDim.x + threadIdx.x; i < NN;
             i += gridDim.x * blockDim.x)
            hist[i] = 0;
    }

    const int lane = threadIdx.x & 63;
    const int wid  = threadIdx.x >> 6;
    const int gw   = blockIdx.x * 4 + wid;
    const int nw   = gridDim.x * 4;
    const int colb = lane & 15;
    const int krow = (lane >> 4) * 8;

    bf16x8 Bf[3][4][2];
    const float* Ws[3] = {WQ, WK, WV};
    #pragma unroll
    for (int m = 0; m < 3; ++m)
        #pragma unroll
        for (int n = 0; n < 4; ++n)
            #pragma unroll
            for (int kh = 0; kh < 2; ++kh) {
                bf16x8 b;
                #pragma unroll
                for (int j = 0; j < 8; ++j)
                    b[j] = f2bf(Ws[m][(size_t)(kh * 32 + krow + j) * 64 + n * 16 + colb]);
                Bf[m][n][kh] = b;
            }

    unsigned short* Outs[3] = {Qb, Kb, Vb};

    for (int tile = gw; tile < NN / 16; tile += nw) {
        const int r0 = tile * 16;
        const float* xr = x + (size_t)(r0 + colb) * 64 + krow;
        f32x4 a0 = *(const f32x4*)(xr);
        f32x4 a1 = *(const f32x4*)(xr + 4);
        f32x4 a2 = *(const f32x4*)(xr + 32);
        f32x4 a3 = *(const f32x4*)(xr + 36);
        bf16x8 Alo, Ahi;
        #pragma unroll
        for (int j = 0; j < 4; ++j) {
            Alo[j]     = f2bf(a0[j]);
            Alo[4 + j] = f2bf(a1[j]);
            Ahi[j]     = f2bf(a2[j]);
            Ahi[4 + j] = f2bf(a3[j]);
        }
        #pragma unroll
        for (int m = 0; m < 3; ++m) {
            #pragma unroll
            for (int n = 0; n < 4; ++n) {
                f32x4 acc = {0.f, 0.f, 0.f, 0.f};
                acc = __builtin_amdgcn_mfma_f32_16x16x32_bf16(Alo, Bf[m][n][0], acc, 0, 0, 0);
                acc = __builtin_amdgcn_mfma_f32_16x16x32_bf16(Ahi, Bf[m][n][1], acc, 0, 0, 0);
                #pragma unroll
                for (int q = 0; q < 4; ++q)
                    Outs[m][(size_t)(r0 + (lane >> 4) * 4 + q) * 64 + n * 16 + colb] =
                        (unsigned short)f2bf(acc[q]);
            }
        }
    }
}

// ---------------- counting sort by dst -----------------------------------
__global__ void hist_kernel(const int* __restrict__ ei, int* __restrict__ hist) {
    const int e = blockIdx.x * blockDim.x + threadIdx.x;
    if (e < NEDGE) atomicAdd(&hist[ei[NEDGE + e]], 1);
}

__global__ __launch_bounds__(256) void scanA_kernel(
    const int* __restrict__ hist, int* __restrict__ ex, int* __restrict__ bsum)
{
    __shared__ int wsum[4];
    const int i = blockIdx.x * 256 + threadIdx.x;
    const int lane = threadIdx.x & 63, wid = threadIdx.x >> 6;
    const int v = (i < NN) ? hist[i] : 0;
    int incl = v;
    #pragma unroll
    for (int off = 1; off < 64; off <<= 1) {
        int t = __shfl_up(incl, off);
        if (lane >= off) incl += t;
    }
    if (lane == 63) wsum[wid] = incl;
    __syncthreads();
    int pre = 0, bt = 0;
    #pragma unroll
    for (int w = 0; w < 4; ++w) { int s = wsum[w]; bt += s; if (w < wid) pre += s; }
    if (i < NN) ex[i] = incl - v + pre;
    if (threadIdx.x == 0) bsum[blockIdx.x] = bt;
}

// scanC now also computes its own block-prefix over bsum (scanB merged in)
__global__ __launch_bounds__(256) void scanC_kernel(
    const int* __restrict__ ex, const int* __restrict__ bsum,
    int* __restrict__ start, int* __restrict__ cursor)
{
    __shared__ int sboff;
    const int b   = blockIdx.x;
    const int tid = threadIdx.x;
    if (tid < 64) {
        int p = 0;
        for (int j = tid; j < b; j += 64) p += bsum[j];
        #pragma unroll
        for (int off = 32; off >= 1; off >>= 1) p += __shfl_down(p, off);
        if (tid == 0) sboff = p;
    }
    __syncthreads();
    const int i = b * 256 + tid;
    if (i < NN) {
        const int s = ex[i] + sboff;
        start[i] = s;
        cursor[i] = s;
    } else if (i == NN) {
        start[NN] = NEDGE;
    }
}

__global__ void scatter_kernel(const int* __restrict__ ei, int* __restrict__ cursor,
                               int2* __restrict__ sorted)
{
    const int e = blockIdx.x * blockDim.x + threadIdx.x;
    if (e < NEDGE) {
        const int dst = ei[NEDGE + e];
        const int pos = atomicAdd(&cursor[dst], 1);
        sorted[pos] = make_int2(ei[e], e);
    }
}

// ---------------- fused aggregation, depth-1 pipelined (round-9 form) -----
__global__ __launch_bounds__(256) void agg_kernel(
    const unsigned short* __restrict__ Qb, const unsigned short* __restrict__ Kb,
    const unsigned short* __restrict__ Vb,
    const float* __restrict__ edge_attr, const float* __restrict__ WE,
    const int* __restrict__ start, const int2* __restrict__ sorted,
    float* __restrict__ out)
{
    const int lane = threadIdx.x & 63;
    const int wid  = threadIdx.x >> 6;
    const int gw   = (blockIdx.x * blockDim.x + threadIdx.x) >> 6;
    const int nw   = (gridDim.x * blockDim.x) >> 6;
    const int colb = lane & 15;
    const int krow = (lane >> 4) * 8;
    const int el   = lane >> 3;     // edge slot 0..7
    const int h    = lane & 7;      // head 0..7
    const float c  = 0.35355339059327373f;   // 1/sqrt(8)

    __shared__ float efs_all[4][16][68];
    float (*efs)[68] = efs_all[wid];

    // WE fragments: 4 col-tiles x 2 k-halves (32 VGPRs)
    bf16x8 Bf[4][2];
    #pragma unroll
    for (int n = 0; n < 4; ++n)
        #pragma unroll
        for (int kh = 0; kh < 2; ++kh) {
            bf16x8 b;
            #pragma unroll
            for (int j = 0; j < 8; ++j)
                b[j] = f2bf(WE[(size_t)(kh * 32 + krow + j) * 64 + n * 16 + colb]);
            Bf[n][kh] = b;
        }

    // prologue: load first dst's state
    int dst = gw;
    int beg = 0, end = 0;
    int2 se = make_int2(0, 0);
    f32x4 a0 = {0,0,0,0}, a1 = {0,0,0,0}, a2 = {0,0,0,0}, a3 = {0,0,0,0};
    if (dst < NN) {
        beg = start[dst]; end = start[dst + 1];
        int rpos = beg + colb;
        if (rpos >= end) rpos = beg;
        if (rpos >= NEDGE) rpos = 0;          // empty trailing dst: clamp
        se = sorted[rpos];
        const float* ear = edge_attr + (size_t)se.y * 64 + krow;
        a0 = *(const f32x4*)(ear);
        a1 = *(const f32x4*)(ear + 4);
        a2 = *(const f32x4*)(ear + 32);
        a3 = *(const f32x4*)(ear + 36);
    }

    for (; dst < NN; dst += nw) {
        const int dn = dst + nw;
        // next-dst start[] issued first (latency hidden under everything below)
        int beg_n = 0, end_n = 0;
        if (dn < NN) { beg_n = start[dn]; end_n = start[dn + 1]; }

        // current-dst K/V/Q gathers, independent of MFMA — issue early
        const int s0 = __shfl(se.x, el);
        const int s1 = __shfl(se.x, el + 8);
        const u16x8 k0v = *(const u16x8*)(Kb + (size_t)s0 * 64 + h * 8);
        const u16x8 v0v = *(const u16x8*)(Vb + (size_t)s0 * 64 + h * 8);
        const u16x8 k1v = *(const u16x8*)(Kb + (size_t)s1 * 64 + h * 8);
        const u16x8 v1v = *(const u16x8*)(Vb + (size_t)s1 * 64 + h * 8);
        const u16x8 qv  = *(const u16x8*)(Qb + (size_t)dst * 64 + h * 8);

        // phase A: pack + MFMA -> efs (first 16-edge batch)
        bf16x8 Alo, Ahi;
        #pragma unroll
        for (int jj = 0; jj < 4; ++jj) {
            Alo[jj]     = f2bf(a0[jj]);
            Alo[4 + jj] = f2bf(a1[jj]);
            Ahi[jj]     = f2bf(a2[jj]);
            Ahi[4 + jj] = f2bf(a3[jj]);
        }
        const int rbase = (lane >> 4) * 4;
        #pragma unroll
        for (int n = 0; n < 4; ++n) {
            f32x4 z = {0.f, 0.f, 0.f, 0.f};
            z = __builtin_amdgcn_mfma_f32_16x16x32_bf16(Alo, Bf[n][0], z, 0, 0, 0);
            z = __builtin_amdgcn_mfma_f32_16x16x32_bf16(Ahi, Bf[n][1], z, 0, 0, 0);
            #pragma unroll
            for (int q = 0; q < 4; ++q)
                efs[rbase + q][n * 16 + colb] = z[q];
        }

        // next-dst dependent chain: sorted -> edge_attr (hidden under phase B)
        int2 se_n = make_int2(0, 0);
        f32x4 a0n = {0,0,0,0}, a1n = {0,0,0,0}, a2n = {0,0,0,0}, a3n = {0,0,0,0};
        if (dn < NN) {
            int rpos_n = beg_n + colb;
            if (rpos_n >= end_n) rpos_n = beg_n;
            if (rpos_n >= NEDGE) rpos_n = 0;   // empty trailing dst: clamp
            se_n = sorted[rpos_n];
            const float* earn = edge_attr + (size_t)se_n.y * 64 + krow;
            a0n = *(const f32x4*)(earn);
            a1n = *(const f32x4*)(earn + 4);
            a2n = *(const f32x4*)(earn + 32);
            a3n = *(const f32x4*)(earn + 36);
        }

        // wave-private LDS; DS pipe in-order per wave
        asm volatile("s_waitcnt lgkmcnt(0)" ::: "memory");
        __builtin_amdgcn_sched_barrier(0);

        // Q -> f32 (once per dst)
        f32x4 q0, q1;
        #pragma unroll
        for (int d = 0; d < 4; ++d) { q0[d] = bf2f(qv[d]); q1[d] = bf2f(qv[4 + d]); }

        // phase B: first batch scores + accumulate
        f32x4 av0 = {0,0,0,0}, av1 = {0,0,0,0};
        float az = 0.f;
        {
            const f32x4 e00 = *(const f32x4*)(&efs[el][h * 8]);
            const f32x4 e01 = *(const f32x4*)(&efs[el][h * 8 + 4]);
            const f32x4 e10 = *(const f32x4*)(&efs[el + 8][h * 8]);
            const f32x4 e11 = *(const f32x4*)(&efs[el + 8][h * 8 + 4]);
            float t0 = 0.f, t1 = 0.f;
            #pragma unroll
            for (int d = 0; d < 4; ++d) {
                t0 += bf2f(k0v[d])     * q0[d] * e00[d];
                t0 += bf2f(k0v[4 + d]) * q1[d] * e01[d];
                t1 += bf2f(k1v[d])     * q0[d] * e10[d];
                t1 += bf2f(k1v[4 + d]) * q1[d] * e11[d];
            }
            const bool act0 = (beg + el)     < end;
            const bool act1 = (beg + el + 8) < end;
            const float sc0 = act0 ? __expf(fminf(fmaxf(t0 * c, -5.f), 5.f)) : 0.f;
            const float sc1 = act1 ? __expf(fminf(fmaxf(t1 * c, -5.f), 5.f)) : 0.f;
            az += sc0 + sc1;
            #pragma unroll
            for (int d = 0; d < 4; ++d) {
                av0[d] += bf2f(v0v[d])     * sc0 + bf2f(v1v[d])     * sc1;
                av1[d] += bf2f(v0v[4 + d]) * sc0 + bf2f(v1v[4 + d]) * sc1;
            }
        }

        // extra batches (deg > 16, ~13% of dsts): serial path
        for (int j = beg + 16; j < end; j += 16) {
            int rpos = j + colb;
            if (rpos >= end) rpos = beg;
            const int2 seb = sorted[rpos];
            const int sb0 = __shfl(seb.x, el);
            const int sb1 = __shfl(seb.x, el + 8);
            const u16x8 kb0 = *(const u16x8*)(Kb + (size_t)sb0 * 64 + h * 8);
            const u16x8 vb0 = *(const u16x8*)(Vb + (size_t)sb0 * 64 + h * 8);
            const u16x8 kb1 = *(const u16x8*)(Kb + (size_t)sb1 * 64 + h * 8);
            const u16x8 vb1 = *(const u16x8*)(Vb + (size_t)sb1 * 64 + h * 8);
            const float* earb = edge_attr + (size_t)seb.y * 64 + krow;
            const f32x4 c0 = *(const f32x4*)(earb);
            const f32x4 c1 = *(const f32x4*)(earb + 4);
            const f32x4 c2 = *(const f32x4*)(earb + 32);
            const f32x4 c3 = *(const f32x4*)(earb + 36);
            bf16x8 Blo, Bhi;
            #pragma unroll
            for (int jj = 0; jj < 4; ++jj) {
                Blo[jj]     = f2bf(c0[jj]);
                Blo[4 + jj] = f2bf(c1[jj]);
                Bhi[jj]     = f2bf(c2[jj]);
                Bhi[4 + jj] = f2bf(c3[jj]);
            }
            #pragma unroll
            for (int n = 0; n < 4; ++n) {
                f32x4 z = {0.f, 0.f, 0.f, 0.f};
                z = __builtin_amdgcn_mfma_f32_16x16x32_bf16(Blo, Bf[n][0], z, 0, 0, 0);
                z = __builtin_amdgcn_mfma_f32_16x16x32_bf16(Bhi, Bf[n][1], z, 0, 0, 0);
                #pragma unroll
                for (int q = 0; q < 4; ++q)
                    efs[rbase + q][n * 16 + colb] = z[q];
            }
            asm volatile("s_waitcnt lgkmcnt(0)" ::: "memory");
            __builtin_amdgcn_sched_barrier(0);
            const f32x4 e00 = *(const f32x4*)(&efs[el][h * 8]);
            const f32x4 e01 = *(const f32x4*)(&efs[el][h * 8 + 4]);
            const f32x4 e10 = *(const f32x4*)(&efs[el + 8][h * 8]);
            const f32x4 e11 = *(const f32x4*)(&efs[el + 8][h * 8 + 4]);
            float t0 = 0.f, t1 = 0.f;
            #pragma unroll
            for (int d = 0; d < 4; ++d) {
                t0 += bf2f(kb0[d])     * q0[d] * e00[d];
                t0 += bf2f(kb0[4 + d]) * q1[d] * e01[d];
                t1 += bf2f(kb1[d])     * q0[d] * e10[d];
                t1 += bf2f(kb1[4 + d]) * q1[d] * e11[d];
            }
            const bool act0 = (j + el)     < end;
            const bool act1 = (j + el + 8) < end;
            const float sc0 = act0 ? __expf(fminf(fmaxf(t0 * c, -5.f), 5.f)) : 0.f;
            const float sc1 = act1 ? __expf(fminf(fmaxf(t1 * c, -5.f), 5.f)) : 0.f;
            az += sc0 + sc1;
            #pragma unroll
            for (int d = 0; d < 4; ++d) {
                av0[d] += bf2f(vb0[d])     * sc0 + bf2f(vb1[d])     * sc1;
                av1[d] += bf2f(vb0[4 + d]) * sc0 + bf2f(vb1[4 + d]) * sc1;
            }
        }

        // reduce across the 8 edge slots for each head
        #pragma unroll
        for (int off = 8; off < 64; off <<= 1) {
            az += __shfl_xor(az, off);
            #pragma unroll
            for (int d = 0; d < 4; ++d) {
                av0[d] += __shfl_xor(av0[d], off);
                av1[d] += __shfl_xor(av1[d], off);
            }
        }

        if (el == 0) {
            const float inv = 1.f / (az + 1e-6f);
            f32x4 o0, o1;
            #pragma unroll
            for (int d = 0; d < 4; ++d) { o0[d] = av0[d] * inv; o1[d] = av1[d] * inv; }
            float* op = out + (size_t)dst * 64 + h * 8;
            *(f32x4*)(op)     = o0;
            *(f32x4*)(op + 4) = o1;
        }

        // rotate pipeline
        beg = beg_n; end = end_n; se = se_n;
        a0 = a0n; a1 = a1n; a2 = a2n; a3 = a3n;
    }
}

// ---------------- fallback path (atomic, small ws) ------------------------
__global__ __launch_bounds__(256) void edge_kernel_fb(
    const float* __restrict__ edge_attr, const float* __restrict__ WE,
    const unsigned short* __restrict__ Qb, const unsigned short* __restrict__ Kb,
    const unsigned short* __restrict__ Vb, const int* __restrict__ ei,
    float* __restrict__ outAcc, float* __restrict__ Z)
{
    const int lane = threadIdx.x & 63;
    const int wid  = threadIdx.x >> 6;
    const int gw   = blockIdx.x * 4 + wid;
    const int nw   = gridDim.x * 4;
    const int colb = lane & 15;
    const int krow = (lane >> 4) * 8;
    const int b8   = (lane >> 3) & 1;

    bf16x8 Bf[4][2];
    #pragma unroll
    for (int n = 0; n < 4; ++n)
        #pragma unroll
        for (int kh = 0; kh < 2; ++kh) {
            bf16x8 b;
            #pragma unroll
            for (int j = 0; j < 8; ++j)
                b[j] = f2bf(WE[(size_t)(kh * 32 + krow + j) * 64 + n * 16 + colb]);
            Bf[n][kh] = b;
        }

    const float inv_sqrt_dh = 0.35355339059327373f;

    for (int tile = gw; tile < NEDGE / 16; tile += nw) {
        const int e0 = tile * 16;
        const float* ear = edge_attr + (size_t)(e0 + colb) * 64 + krow;
        f32x4 a0 = *(const f32x4*)(ear);
        f32x4 a1 = *(const f32x4*)(ear + 4);
        f32x4 a2 = *(const f32x4*)(ear + 32);
        f32x4 a3 = *(const f32x4*)(ear + 36);
        bf16x8 Alo, Ahi;
        #pragma unroll
        for (int j = 0; j < 4; ++j) {
            Alo[j]     = f2bf(a0[j]);
            Alo[4 + j] = f2bf(a1[j]);
            Ahi[j]     = f2bf(a2[j]);
            Ahi[4 + j] = f2bf(a3[j]);
        }
        f32x4 acc[4];
        #pragma unroll
        for (int n = 0; n < 4; ++n) {
            f32x4 z = {0.f, 0.f, 0.f, 0.f};
            z = __builtin_amdgcn_mfma_f32_16x16x32_bf16(Alo, Bf[n][0], z, 0, 0, 0);
            z = __builtin_amdgcn_mfma_f32_16x16x32_bf16(Ahi, Bf[n][1], z, 0, 0, 0);
            acc[n] = z;
        }
        int srcq[4], dstq[4];
        #pragma unroll
        for (int q = 0; q < 4; ++q) {
            const int erl = (lane >> 4) * 4 + q;
            srcq[q] = ei[e0 + erl];
            dstq[q] = ei[NEDGE + e0 + erl];
        }
        float sc[4][4];
        #pragma unroll
        for (int q = 0; q < 4; ++q) {
            #pragma unroll
            for (int n = 0; n < 4; ++n) {
                const int cidx = n * 16 + colb;
                const float kv = bf2f(Kb[(size_t)srcq[q] * 64 + cidx]);
                const float qv = bf2f(Qb[(size_t)dstq[q] * 64 + cidx]);
                float t = kv * qv * acc[n][q];
                t += __shfl_xor(t, 1);
                t += __shfl_xor(t, 2);
                t += __shfl_xor(t, 4);
                const float s = fminf(fmaxf(t * inv_sqrt_dh, -5.0f), 5.0f);
                sc[q][n] = __expf(s);
            }
        }
        #pragma unroll
        for (int q = 0; q < 4; ++q) {
            #pragma unroll
            for (int n = 0; n < 4; ++n) {
                const int cidx = n * 16 + colb;
                const float vv = bf2f(Vb[(size_t)srcq[q] * 64 + cidx]);
                unsafeAtomicAdd(&outAcc[(size_t)dstq[q] * 64 + cidx], vv * sc[q][n]);
                if ((lane & 7) == 0) {
                    const int hh = 2 * n + b8;
                    unsafeAtomicAdd(&Z[(size_t)dstq[q] * 8 + hh], sc[q][n]);
                }
            }
        }
    }
}

__global__ void finalize_fb(float* __restrict__ out, const float* __restrict__ Z) {
    const int i = blockIdx.x * blockDim.x + threadIdx.x;
    if (i < NN * 64) {
        const int node = i >> 6;
        const int h    = (i >> 3) & 7;
        out[i] = out[i] / (Z[node * 8 + h] + 1e-6f);
    }
}

extern "C" void kernel_launch(void* const* d_in, const int* in_sizes, int n_in,
                              void* d_out, int out_size, void* d_ws, size_t ws_size,
                              hipStream_t stream) {
    const float* x         = (const float*)d_in[0];
    const float* edge_attr = (const float*)d_in[1];
    const float* WQ        = (const float*)d_in[2];
    const float* WK        = (const float*)d_in[3];
    const float* WV        = (const float*)d_in[4];
    const float* WE        = (const float*)d_in[5];
    const int*   ei        = (const int*)d_in[6];
    float* out = (float*)d_out;

    char* base = (char*)d_ws;
    unsigned short* Qb = (unsigned short*)(base + OFF_QB);
    unsigned short* Kb = (unsigned short*)(base + OFF_KB);
    unsigned short* Vb = (unsigned short*)(base + OFF_VB);

    if (ws_size >= WS_NEED) {
        int2* sorted = (int2*)(base + OFF_SRT);
        int* hist    = (int*)(base + OFF_HIST);
        int* ex      = (int*)(base + OFF_EX);
        int* bsum    = (int*)(base + OFF_BSUM);
        int* start   = (int*)(base + OFF_START);
        int* cursor  = (int*)(base + OFF_CUR);

        qkv_kernel<<<1563, 256, 0, stream>>>(x, WQ, WK, WV, Qb, Kb, Vb, hist);
        hist_kernel<<<(NEDGE + 255) / 256, 256, 0, stream>>>(ei, hist);
        scanA_kernel<<<NB_SCAN, 256, 0, stream>>>(hist, ex, bsum);
        scanC_kernel<<<NB_SCAN, 256, 0, stream>>>(ex, bsum, start, cursor);
        scatter_kernel<<<(NEDGE + 255) / 256, 256, 0, stream>>>(ei, cursor, sorted);
        agg_kernel<<<4096, 256, 0, stream>>>(Qb, Kb, Vb, edge_attr, WE, start, sorted, out);
    } else {
        // fallback: atomic path
        float* Z = (float*)(base + OFF_SRT);
        qkv_kernel<<<1563, 256, 0, stream>>>(x, WQ, WK, WV, Qb, Kb, Vb, nullptr);
        hipMemsetAsync(d_out, 0, (size_t)NN * 64 * sizeof(float), stream);
        hipMemsetAsync(Z, 0, (size_t)NN * 8 * sizeof(float), stream);
        edge_kernel_fb<<<2048, 256, 0, stream>>>(edge_attr, WE, Qb, Kb, Vb, ei, out, Z);
        finalize_fb<<<(NN * 64 + 255) / 256, 256, 0, stream>>>(out, Z);
    }
}